// Round 20
// baseline (185.633 us; speedup 1.0000x reference)
//
#include <hip/hip_runtime.h>
#include <math.h>

namespace {
constexpr int RADIUS = 9;
constexpr float EPSV = 1e-5f;
constexpr int N_ = 2, C_ = 64, H_ = 128, W_ = 192;
constexpr int HW  = H_ * W_;            // 24576
constexpr int CHW = C_ * HW;
constexpr size_t OUT1 = (size_t)N_ * 81 * HW;

constexpr int XT = 64, YT = 4;          // spatial tile; i fully in grid.z
constexpr int NT = 512;                 // 8 waves; wave = channel-group of 8
constexpr int NW = 8;
constexpr int ROUNDS = 8;               // 1 channel / wave / round
constexpr int MROWS = 4;
constexpr int NCH = 19;
constexpr int MCOLS = 76;
constexpr int MAP_SLOTS = MROWS * NCH;  // 76
constexpr int SLOT_F = NT * 4;          // 2048 floats per slot-plane
constexpr int OFF_INVM = 3 * SLOT_F;    // 6144 (3 reduce planes)
constexpr int LDS_F = OFF_INVM + MROWS * MCOLS;   // 6448 floats = 25792 B
}

// ---------------------------------------------------------------------------
// Kernel 1: invM (map channel-norms) + left-edge strips.
//   strip [(n*C+c)*H + y][0..3] = {m0,m0,m0,m0}
//   strip2[(n*C+c)*H + y][0..3] = {m0,m0,m1,m2}   (window starting at x=-1)
// ---------------------------------------------------------------------------
__global__ __launch_bounds__(256)
void norms_kernel(const float* __restrict__ mp,
                  float* __restrict__ invM,
                  float* __restrict__ strip,
                  float* __restrict__ strip2) {
    __shared__ float4 sM[8][32];
    const int tid = threadIdx.x;
    const int cg = tid >> 5;               // 0..7 (8 channels each)
    const int s  = tid & 31;
    const int q4 = blockIdx.x * 32 + s;    // [0, 12288)
    const int n = q4 / (HW / 4);
    const int pix = (q4 - n * (HW / 4)) * 4;
    const int y = pix / W_;
    const int x = pix - y * W_;
    const float* pm = mp + (size_t)n * CHW + pix;
    const bool e = (x == 0);
    float* sp  = strip  + ((size_t)(n * C_ + cg * 8) * H_ + y) * 4;
    float* sp2 = strip2 + ((size_t)(n * C_ + cg * 8) * H_ + y) * 4;

    float4 sm = {0.f, 0.f, 0.f, 0.f};
#pragma unroll
    for (int cc = 0; cc < 8; ++cc) {
        float4 b = *(const float4*)(pm + (size_t)(cg * 8 + cc) * HW);
        sm.x = fmaf(b.x, b.x, sm.x); sm.y = fmaf(b.y, b.y, sm.y);
        sm.z = fmaf(b.z, b.z, sm.z); sm.w = fmaf(b.w, b.w, sm.w);
        if (e) {
            float4 v1 = {b.x, b.x, b.x, b.x};
            float4 v2 = {b.x, b.x, b.y, b.z};
            *(float4*)(sp  + (size_t)cc * H_ * 4) = v1;
            *(float4*)(sp2 + (size_t)cc * H_ * 4) = v2;
        }
    }
    sM[cg][s] = sm;
    __syncthreads();
    if (tid < 32) {
        float4 b = sM[0][tid];
#pragma unroll
        for (int g = 1; g < 8; ++g) {
            float4 v = sM[g][tid];
            b.x += v.x; b.y += v.y; b.z += v.z; b.w += v.w;
        }
        int q4b = blockIdx.x * 32 + tid;
        int nb = q4b / (HW / 4);
        int pixb = (q4b - nb * (HW / 4)) * 4;
        float4 vm;
        vm.x = 1.f / (sqrtf(b.x) + EPSV); vm.y = 1.f / (sqrtf(b.y) + EPSV);
        vm.z = 1.f / (sqrtf(b.z) + EPSV); vm.w = 1.f / (sqrtf(b.w) + EPSV);
        *(float4*)(invM + (size_t)nb * HW + pixb) = vm;
    }
}

// ---------------------------------------------------------------------------
// Kernel 2: raw correlation + inline img-norm. No LDS/barriers in main loop.
// 8-way c-split (8 waves x 8 ch) doubles wave supply to 54/CU; residency 32.
// Per round: 3 dword-aligned 16B map loads + 1 img float4; 40 FMAs.
//   dotRaw[p,(i,j)] = sum_c map[c, clamp(p+(i,j)-9)] * img[c, p]
//   out_diss = invI[p]*dotRaw ;  out_cos = 1 - invM[p']*out_diss
// ---------------------------------------------------------------------------
#define STORE_J(PLANE, J)                                                      \
    do {                                                                       \
        const int j_ = (J);                                                    \
        float4 s_ = {0.f, 0.f, 0.f, 0.f};                                      \
        _Pragma("unroll")                                                      \
        for (int g = 0; g < NW; ++g) {                                         \
            float4 v_ = *(const float4*)&smem[((PLANE) * SLOT_F) +             \
                                              (g * 64 + lane) * 4];            \
            s_.x += v_.x; s_.y += v_.y; s_.z += v_.z; s_.w += v_.w;            \
        }                                                                      \
        float4 vd_, vc_;                                                       \
        vd_.x = s_.x * vI.x; vd_.y = s_.y * vI.y;                              \
        vd_.z = s_.z * vI.z; vd_.w = s_.w * vI.w;                              \
        vc_.x = 1.f - vd_.x * wmRow[j_ + 0];                                   \
        vc_.y = 1.f - vd_.y * wmRow[j_ + 1];                                   \
        vc_.z = 1.f - vd_.z * wmRow[j_ + 2];                                   \
        vc_.w = 1.f - vd_.w * wmRow[j_ + 3];                                   \
        *(float4*)(ocB + (size_t)j_ * HW) = vc_;                               \
        *(float4*)(ocB + OUT1 + (size_t)j_ * HW) = vd_;                        \
    } while (0)

__global__ __launch_bounds__(NT, 8)
void corr_kernel(const float* __restrict__ img,
                 const float* __restrict__ mp,
                 const float* __restrict__ invMg,
                 const float* __restrict__ strip,
                 const float* __restrict__ strip2,
                 float* __restrict__ out) {
    __shared__ float smem[LDS_F];

    const int bz = blockIdx.z;             // n*9 + i
    const int n    = bz / RADIUS;
    const int iOff = bz - n * RADIUS;
    const int x0 = blockIdx.x * XT;
    const int y0 = blockIdx.y * YT;
    const int tid = threadIdx.x;
    const int w    = tid >> 6;             // wave = channel group (8 ch), 0..7
    const int lane = tid & 63;
    const int ty = lane >> 4;              // 0..3
    const int xc = lane & 15;              // 0..15
    const int ch0 = w * 8;

    const float* imgN = img + (size_t)n * CHW;
    const float* mapN = mp  + (size_t)n * CHW;

    // ---- invM halo (76 float4; epilogue-only, synced by epilogue barrier) ----
    if (tid < MAP_SLOTS) {
        int r = tid / NCH, k = tid - r * NCH;
        int gy = min(max(y0 + iOff - RADIUS + r, 0), H_ - 1);
        int gxs = x0 - 12 + 4 * k;
        const float* src = invMg + n * HW + (size_t)gy * W_;
        float4 v;
        if (gxs >= 0) v = *(const float4*)(src + gxs);
        else { float s0 = src[0]; v.x = s0; v.y = s0; v.z = s0; v.w = s0; }
        *(float4*)&smem[OFF_INVM + r * MCOLS + 4 * k] = v;
    }

    // ---- per-lane direct-read descriptors (3 chunks, window = x0+4xc-9+[0,12)) ----
    const int gy = min(max(y0 + ty + iOff - RADIUS, 0), H_ - 1);
    const float* rowp = mapN + (size_t)ch0 * HW + (size_t)gy * W_;
    const float* stripRow  = strip  + ((size_t)(n * C_ + ch0) * H_ + gy) * 4;
    const float* stripRow2 = strip2 + ((size_t)(n * C_ + ch0) * H_ + gy) * 4;
    const float *pd0, *pd1, *pd2;
    int sd0, sd1, sd2;
    {
        const int gxb = x0 + 4 * xc - 9;
        if (gxb <= -4)     { pd0 = stripRow;  sd0 = H_ * 4; }
        else if (gxb < 0)  { pd0 = stripRow2; sd0 = H_ * 4; }   // gxb == -1
        else               { pd0 = rowp + gxb; sd0 = HW; }
        const int g1 = gxb + 4;
        if (g1 <= -4)      { pd1 = stripRow;  sd1 = H_ * 4; }
        else if (g1 < 0)   { pd1 = stripRow2; sd1 = H_ * 4; }
        else               { pd1 = rowp + g1;  sd1 = HW; }
        const int g2 = gxb + 8;
        if (g2 < 0)        { pd2 = stripRow2; sd2 = H_ * 4; }   // g2 == -1 only
        else               { pd2 = rowp + g2;  sd2 = HW; }
    }
    const float* pI = imgN + (size_t)ch0 * HW + (size_t)(y0 + ty) * W_ + x0 + 4 * xc;

    float acc[4][RADIUS];
#pragma unroll
    for (int p = 0; p < 4; ++p)
#pragma unroll
        for (int j = 0; j < RADIUS; ++j) acc[p][j] = 0.f;
    float si[4] = {0.f, 0.f, 0.f, 0.f};

    // ---- main loop: pure register dataflow, no LDS, no barriers ----
#pragma unroll 4
    for (int ri = 0; ri < ROUNDS; ++ri) {
        float wreg[12];
        __builtin_memcpy(&wreg[0], pd0 + (size_t)ri * sd0, 16);
        __builtin_memcpy(&wreg[4], pd1 + (size_t)ri * sd1, 16);
        __builtin_memcpy(&wreg[8], pd2 + (size_t)ri * sd2, 16);
        const float4 a4 = *(const float4*)(pI + (size_t)ri * HW);
        const float a[4] = {a4.x, a4.y, a4.z, a4.w};
        si[0] = fmaf(a[0], a[0], si[0]);
        si[1] = fmaf(a[1], a[1], si[1]);
        si[2] = fmaf(a[2], a[2], si[2]);
        si[3] = fmaf(a[3], a[3], si[3]);
#pragma unroll
        for (int p = 0; p < 4; ++p)
#pragma unroll
            for (int j = 0; j < RADIUS; ++j)
                acc[p][j] = fmaf(wreg[p + j], a[p], acc[p][j]);
    }

    // ==== epilogue: 8-way cross-wave reduce in 4 passes of <=3 planes ====
    const int slot4 = tid * 4;
    const int y  = y0 + ty;
    const int xb = x0 + 4 * xc;
    const float* wmRow = &smem[OFF_INVM + ty * MCOLS + 4 * xc + 3];
    float* ocB = out + (size_t)(n * 81 + iOff * RADIUS) * HW + (size_t)y * W_ + xb;

    __syncthreads();                       // invM halo ready; LDS free
    // ---- pass 1: planes = {si, q0, q1} ----
    { float4 v = {si[0], si[1], si[2], si[3]}; *(float4*)&smem[0 * SLOT_F + slot4] = v; }
    { float4 v = {acc[0][0], acc[1][0], acc[2][0], acc[3][0]}; *(float4*)&smem[1 * SLOT_F + slot4] = v; }
    { float4 v = {acc[0][1], acc[1][1], acc[2][1], acc[3][1]}; *(float4*)&smem[2 * SLOT_F + slot4] = v; }
    __syncthreads();
    float4 sv = {0.f, 0.f, 0.f, 0.f};
#pragma unroll
    for (int g = 0; g < NW; ++g) {
        float4 v = *(const float4*)&smem[0 * SLOT_F + (g * 64 + lane) * 4];
        sv.x += v.x; sv.y += v.y; sv.z += v.z; sv.w += v.w;
    }
    float4 vI;
    vI.x = 1.f / (sqrtf(sv.x) + EPSV);
    vI.y = 1.f / (sqrtf(sv.y) + EPSV);
    vI.z = 1.f / (sqrtf(sv.z) + EPSV);
    vI.w = 1.f / (sqrtf(sv.w) + EPSV);
    if (w == 0) STORE_J(1, 0);
    if (w == 1) STORE_J(2, 1);
    __syncthreads();
    // ---- pass 2: planes = {q2, q3, q4} ----
    { float4 v = {acc[0][2], acc[1][2], acc[2][2], acc[3][2]}; *(float4*)&smem[0 * SLOT_F + slot4] = v; }
    { float4 v = {acc[0][3], acc[1][3], acc[2][3], acc[3][3]}; *(float4*)&smem[1 * SLOT_F + slot4] = v; }
    { float4 v = {acc[0][4], acc[1][4], acc[2][4], acc[3][4]}; *(float4*)&smem[2 * SLOT_F + slot4] = v; }
    __syncthreads();
    if (w == 2) STORE_J(0, 2);
    if (w == 3) STORE_J(1, 3);
    if (w == 4) STORE_J(2, 4);
    __syncthreads();
    // ---- pass 3: planes = {q5, q6, q7} ----
    { float4 v = {acc[0][5], acc[1][5], acc[2][5], acc[3][5]}; *(float4*)&smem[0 * SLOT_F + slot4] = v; }
    { float4 v = {acc[0][6], acc[1][6], acc[2][6], acc[3][6]}; *(float4*)&smem[1 * SLOT_F + slot4] = v; }
    { float4 v = {acc[0][7], acc[1][7], acc[2][7], acc[3][7]}; *(float4*)&smem[2 * SLOT_F + slot4] = v; }
    __syncthreads();
    if (w == 5) STORE_J(0, 5);
    if (w == 6) STORE_J(1, 6);
    if (w == 7) STORE_J(2, 7);
    __syncthreads();
    // ---- pass 4: plane = {q8} ----
    { float4 v = {acc[0][8], acc[1][8], acc[2][8], acc[3][8]}; *(float4*)&smem[0 * SLOT_F + slot4] = v; }
    __syncthreads();
    if (w == 0) STORE_J(0, 8);
}

extern "C" void kernel_launch(void* const* d_in, const int* in_sizes, int n_in,
                              void* d_out, int out_size, void* d_ws, size_t ws_size,
                              hipStream_t stream) {
    const float* img = (const float*)d_in[0];
    const float* mp  = (const float*)d_in[1];
    float* out    = (float*)d_out;
    float* invM   = (float*)d_ws;                 // N_*HW floats
    float* strip  = invM  + N_ * HW;              // N_*C_*H_*4 floats
    float* strip2 = strip + (size_t)N_ * C_ * H_ * 4;

    norms_kernel<<<(N_ * HW / 4) / 32, 256, 0, stream>>>(mp, invM, strip, strip2);

    dim3 grid(W_ / XT, H_ / YT, N_ * RADIUS);     // 3 x 32 x 18 = 1728 blocks
    corr_kernel<<<grid, NT, 0, stream>>>(img, mp, invM, strip, strip2, out);
}

// Round 21
// 49.144 us; speedup vs baseline: 3.7773x; 3.7773x over previous
//
#include <hip/hip_runtime.h>
#include <math.h>

namespace {
constexpr int RADIUS = 9;
constexpr float EPSV = 1e-5f;
constexpr int N_ = 2, C_ = 64, H_ = 128, W_ = 192;
constexpr int HW  = H_ * W_;            // 24576
constexpr int CHW = C_ * HW;
constexpr size_t OUT1 = (size_t)N_ * 81 * HW;

constexpr int XT = 64, YT = 4;          // spatial tile; i fully in grid.z
constexpr int NT = 512;                 // 8 waves; wave = channel-group of 8
constexpr int NW = 8;
constexpr int ROUNDS = 8;               // 1 channel / wave / round
constexpr int MROWS = 4;
constexpr int NCH = 19;
constexpr int MCOLS = 76;
constexpr int MAP_SLOTS = MROWS * NCH;  // 76
constexpr int SLOT_F = NT * 4;          // 2048 floats per slot-plane
constexpr int OFF_INVM = 3 * SLOT_F;    // 6144 (3 reduce planes)
constexpr int LDS_F = OFF_INVM + MROWS * MCOLS;   // 6448 floats = 25792 B
}

// ---------------------------------------------------------------------------
// Kernel 1: invM (map channel-norms) + left-edge strips.
//   strip [(n*C+c)*H + y][0..3] = {m0,m0,m0,m0}
//   strip2[(n*C+c)*H + y][0..3] = {m0,m0,m1,m2}   (window starting at x=-1)
// ---------------------------------------------------------------------------
__global__ __launch_bounds__(256)
void norms_kernel(const float* __restrict__ mp,
                  float* __restrict__ invM,
                  float* __restrict__ strip,
                  float* __restrict__ strip2) {
    __shared__ float4 sM[8][32];
    const int tid = threadIdx.x;
    const int cg = tid >> 5;               // 0..7 (8 channels each)
    const int s  = tid & 31;
    const int q4 = blockIdx.x * 32 + s;    // [0, 12288)
    const int n = q4 / (HW / 4);
    const int pix = (q4 - n * (HW / 4)) * 4;
    const int y = pix / W_;
    const int x = pix - y * W_;
    const float* pm = mp + (size_t)n * CHW + pix;
    const bool e = (x == 0);
    float* sp  = strip  + ((size_t)(n * C_ + cg * 8) * H_ + y) * 4;
    float* sp2 = strip2 + ((size_t)(n * C_ + cg * 8) * H_ + y) * 4;

    float4 sm = {0.f, 0.f, 0.f, 0.f};
#pragma unroll
    for (int cc = 0; cc < 8; ++cc) {
        float4 b = *(const float4*)(pm + (size_t)(cg * 8 + cc) * HW);
        sm.x = fmaf(b.x, b.x, sm.x); sm.y = fmaf(b.y, b.y, sm.y);
        sm.z = fmaf(b.z, b.z, sm.z); sm.w = fmaf(b.w, b.w, sm.w);
        if (e) {
            float4 v1 = {b.x, b.x, b.x, b.x};
            float4 v2 = {b.x, b.x, b.y, b.z};
            *(float4*)(sp  + (size_t)cc * H_ * 4) = v1;
            *(float4*)(sp2 + (size_t)cc * H_ * 4) = v2;
        }
    }
    sM[cg][s] = sm;
    __syncthreads();
    if (tid < 32) {
        float4 b = sM[0][tid];
#pragma unroll
        for (int g = 1; g < 8; ++g) {
            float4 v = sM[g][tid];
            b.x += v.x; b.y += v.y; b.z += v.z; b.w += v.w;
        }
        int q4b = blockIdx.x * 32 + tid;
        int nb = q4b / (HW / 4);
        int pixb = (q4b - nb * (HW / 4)) * 4;
        float4 vm;
        vm.x = 1.f / (sqrtf(b.x) + EPSV); vm.y = 1.f / (sqrtf(b.y) + EPSV);
        vm.z = 1.f / (sqrtf(b.z) + EPSV); vm.w = 1.f / (sqrtf(b.w) + EPSV);
        *(float4*)(invM + (size_t)nb * HW + pixb) = vm;
    }
}

// ---------------------------------------------------------------------------
// Kernel 2: raw correlation + inline img-norm. No LDS/barriers in main loop.
// 8-way c-split (8 waves x 8 ch): 54 waves/CU supply, ~32 resident at
// natural VGPR (~60). NO occupancy promise (R3/R7/R20 spill trap).
// Per round: 3 dword-aligned 16B map loads + 1 img float4; 40 FMAs.
//   dotRaw[p,(i,j)] = sum_c map[c, clamp(p+(i,j)-9)] * img[c, p]
//   out_diss = invI[p]*dotRaw ;  out_cos = 1 - invM[p']*out_diss
// ---------------------------------------------------------------------------
#define STORE_J(PLANE, J)                                                      \
    do {                                                                       \
        const int j_ = (J);                                                    \
        float4 s_ = {0.f, 0.f, 0.f, 0.f};                                      \
        _Pragma("unroll")                                                      \
        for (int g = 0; g < NW; ++g) {                                         \
            float4 v_ = *(const float4*)&smem[((PLANE) * SLOT_F) +             \
                                              (g * 64 + lane) * 4];            \
            s_.x += v_.x; s_.y += v_.y; s_.z += v_.z; s_.w += v_.w;            \
        }                                                                      \
        float4 vd_, vc_;                                                       \
        vd_.x = s_.x * vI.x; vd_.y = s_.y * vI.y;                              \
        vd_.z = s_.z * vI.z; vd_.w = s_.w * vI.w;                              \
        vc_.x = 1.f - vd_.x * wmRow[j_ + 0];                                   \
        vc_.y = 1.f - vd_.y * wmRow[j_ + 1];                                   \
        vc_.z = 1.f - vd_.z * wmRow[j_ + 2];                                   \
        vc_.w = 1.f - vd_.w * wmRow[j_ + 3];                                   \
        *(float4*)(ocB + (size_t)j_ * HW) = vc_;                               \
        *(float4*)(ocB + OUT1 + (size_t)j_ * HW) = vd_;                        \
    } while (0)

__global__ __launch_bounds__(NT)
void corr_kernel(const float* __restrict__ img,
                 const float* __restrict__ mp,
                 const float* __restrict__ invMg,
                 const float* __restrict__ strip,
                 const float* __restrict__ strip2,
                 float* __restrict__ out) {
    __shared__ float smem[LDS_F];

    const int bz = blockIdx.z;             // n*9 + i
    const int n    = bz / RADIUS;
    const int iOff = bz - n * RADIUS;
    const int x0 = blockIdx.x * XT;
    const int y0 = blockIdx.y * YT;
    const int tid = threadIdx.x;
    const int w    = tid >> 6;             // wave = channel group (8 ch), 0..7
    const int lane = tid & 63;
    const int ty = lane >> 4;              // 0..3
    const int xc = lane & 15;              // 0..15
    const int ch0 = w * 8;

    const float* imgN = img + (size_t)n * CHW;
    const float* mapN = mp  + (size_t)n * CHW;

    // ---- invM halo (76 float4; epilogue-only, synced by epilogue barrier) ----
    if (tid < MAP_SLOTS) {
        int r = tid / NCH, k = tid - r * NCH;
        int gy = min(max(y0 + iOff - RADIUS + r, 0), H_ - 1);
        int gxs = x0 - 12 + 4 * k;
        const float* src = invMg + n * HW + (size_t)gy * W_;
        float4 v;
        if (gxs >= 0) v = *(const float4*)(src + gxs);
        else { float s0 = src[0]; v.x = s0; v.y = s0; v.z = s0; v.w = s0; }
        *(float4*)&smem[OFF_INVM + r * MCOLS + 4 * k] = v;
    }

    // ---- per-lane direct-read descriptors (3 chunks, window = x0+4xc-9+[0,12)) ----
    const int gy = min(max(y0 + ty + iOff - RADIUS, 0), H_ - 1);
    const float* rowp = mapN + (size_t)ch0 * HW + (size_t)gy * W_;
    const float* stripRow  = strip  + ((size_t)(n * C_ + ch0) * H_ + gy) * 4;
    const float* stripRow2 = strip2 + ((size_t)(n * C_ + ch0) * H_ + gy) * 4;
    const float *pd0, *pd1, *pd2;
    int sd0, sd1, sd2;
    {
        const int gxb = x0 + 4 * xc - 9;
        if (gxb <= -4)     { pd0 = stripRow;  sd0 = H_ * 4; }
        else if (gxb < 0)  { pd0 = stripRow2; sd0 = H_ * 4; }   // gxb == -1
        else               { pd0 = rowp + gxb; sd0 = HW; }
        const int g1 = gxb + 4;
        if (g1 <= -4)      { pd1 = stripRow;  sd1 = H_ * 4; }
        else if (g1 < 0)   { pd1 = stripRow2; sd1 = H_ * 4; }
        else               { pd1 = rowp + g1;  sd1 = HW; }
        const int g2 = gxb + 8;
        if (g2 < 0)        { pd2 = stripRow2; sd2 = H_ * 4; }   // g2 == -1 only
        else               { pd2 = rowp + g2;  sd2 = HW; }
    }
    const float* pI = imgN + (size_t)ch0 * HW + (size_t)(y0 + ty) * W_ + x0 + 4 * xc;

    float acc[4][RADIUS];
#pragma unroll
    for (int p = 0; p < 4; ++p)
#pragma unroll
        for (int j = 0; j < RADIUS; ++j) acc[p][j] = 0.f;
    float si[4] = {0.f, 0.f, 0.f, 0.f};

    // ---- main loop: pure register dataflow, no LDS, no barriers ----
#pragma unroll 4
    for (int ri = 0; ri < ROUNDS; ++ri) {
        float wreg[12];
        __builtin_memcpy(&wreg[0], pd0 + (size_t)ri * sd0, 16);
        __builtin_memcpy(&wreg[4], pd1 + (size_t)ri * sd1, 16);
        __builtin_memcpy(&wreg[8], pd2 + (size_t)ri * sd2, 16);
        const float4 a4 = *(const float4*)(pI + (size_t)ri * HW);
        const float a[4] = {a4.x, a4.y, a4.z, a4.w};
        si[0] = fmaf(a[0], a[0], si[0]);
        si[1] = fmaf(a[1], a[1], si[1]);
        si[2] = fmaf(a[2], a[2], si[2]);
        si[3] = fmaf(a[3], a[3], si[3]);
#pragma unroll
        for (int p = 0; p < 4; ++p)
#pragma unroll
            for (int j = 0; j < RADIUS; ++j)
                acc[p][j] = fmaf(wreg[p + j], a[p], acc[p][j]);
    }

    // ==== epilogue: 8-way cross-wave reduce in 4 passes of <=3 planes ====
    const int slot4 = tid * 4;
    const int y  = y0 + ty;
    const int xb = x0 + 4 * xc;
    const float* wmRow = &smem[OFF_INVM + ty * MCOLS + 4 * xc + 3];
    float* ocB = out + (size_t)(n * 81 + iOff * RADIUS) * HW + (size_t)y * W_ + xb;

    __syncthreads();                       // invM halo ready; LDS free
    // ---- pass 1: planes = {si, q0, q1} ----
    { float4 v = {si[0], si[1], si[2], si[3]}; *(float4*)&smem[0 * SLOT_F + slot4] = v; }
    { float4 v = {acc[0][0], acc[1][0], acc[2][0], acc[3][0]}; *(float4*)&smem[1 * SLOT_F + slot4] = v; }
    { float4 v = {acc[0][1], acc[1][1], acc[2][1], acc[3][1]}; *(float4*)&smem[2 * SLOT_F + slot4] = v; }
    __syncthreads();
    float4 sv = {0.f, 0.f, 0.f, 0.f};
#pragma unroll
    for (int g = 0; g < NW; ++g) {
        float4 v = *(const float4*)&smem[0 * SLOT_F + (g * 64 + lane) * 4];
        sv.x += v.x; sv.y += v.y; sv.z += v.z; sv.w += v.w;
    }
    float4 vI;
    vI.x = 1.f / (sqrtf(sv.x) + EPSV);
    vI.y = 1.f / (sqrtf(sv.y) + EPSV);
    vI.z = 1.f / (sqrtf(sv.z) + EPSV);
    vI.w = 1.f / (sqrtf(sv.w) + EPSV);
    if (w == 0) STORE_J(1, 0);
    if (w == 1) STORE_J(2, 1);
    __syncthreads();
    // ---- pass 2: planes = {q2, q3, q4} ----
    { float4 v = {acc[0][2], acc[1][2], acc[2][2], acc[3][2]}; *(float4*)&smem[0 * SLOT_F + slot4] = v; }
    { float4 v = {acc[0][3], acc[1][3], acc[2][3], acc[3][3]}; *(float4*)&smem[1 * SLOT_F + slot4] = v; }
    { float4 v = {acc[0][4], acc[1][4], acc[2][4], acc[3][4]}; *(float4*)&smem[2 * SLOT_F + slot4] = v; }
    __syncthreads();
    if (w == 2) STORE_J(0, 2);
    if (w == 3) STORE_J(1, 3);
    if (w == 4) STORE_J(2, 4);
    __syncthreads();
    // ---- pass 3: planes = {q5, q6, q7} ----
    { float4 v = {acc[0][5], acc[1][5], acc[2][5], acc[3][5]}; *(float4*)&smem[0 * SLOT_F + slot4] = v; }
    { float4 v = {acc[0][6], acc[1][6], acc[2][6], acc[3][6]}; *(float4*)&smem[1 * SLOT_F + slot4] = v; }
    { float4 v = {acc[0][7], acc[1][7], acc[2][7], acc[3][7]}; *(float4*)&smem[2 * SLOT_F + slot4] = v; }
    __syncthreads();
    if (w == 5) STORE_J(0, 5);
    if (w == 6) STORE_J(1, 6);
    if (w == 7) STORE_J(2, 7);
    __syncthreads();
    // ---- pass 4: plane = {q8} ----
    { float4 v = {acc[0][8], acc[1][8], acc[2][8], acc[3][8]}; *(float4*)&smem[0 * SLOT_F + slot4] = v; }
    __syncthreads();
    if (w == 0) STORE_J(0, 8);
}

extern "C" void kernel_launch(void* const* d_in, const int* in_sizes, int n_in,
                              void* d_out, int out_size, void* d_ws, size_t ws_size,
                              hipStream_t stream) {
    const float* img = (const float*)d_in[0];
    const float* mp  = (const float*)d_in[1];
    float* out    = (float*)d_out;
    float* invM   = (float*)d_ws;                 // N_*HW floats
    float* strip  = invM  + N_ * HW;              // N_*C_*H_*4 floats
    float* strip2 = strip + (size_t)N_ * C_ * H_ * 4;

    norms_kernel<<<(N_ * HW / 4) / 32, 256, 0, stream>>>(mp, invM, strip, strip2);

    dim3 grid(W_ / XT, H_ / YT, N_ * RADIUS);     // 3 x 32 x 18 = 1728 blocks
    corr_kernel<<<grid, NT, 0, stream>>>(img, mp, invM, strip, strip2, out);
}

// Round 22
// 32.988 us; speedup vs baseline: 5.6273x; 1.4898x over previous
//
#include <hip/hip_runtime.h>
#include <math.h>

namespace {
constexpr int RADIUS = 9;
constexpr float EPSV = 1e-5f;
constexpr int N_ = 2, C_ = 64, H_ = 128, W_ = 192;
constexpr int HW  = H_ * W_;            // 24576
constexpr int CHW = C_ * HW;
constexpr size_t OUT1 = (size_t)N_ * 81 * HW;

constexpr int XT = 64, YT = 4;          // spatial tile; i fully in grid.z
constexpr int NT = 256;                 // 4 waves; wave = channel-group of 16
constexpr int NW = 4;
constexpr int ROUNDS = 16;              // 1 channel / wave / round
constexpr int MROWS = 4;
constexpr int NCH = 19;
constexpr int MCOLS = 76;
constexpr int MAP_SLOTS = MROWS * NCH;  // 76
constexpr int OFF_INVM = 5 * 256 * 4;   // 5120 (epilogue reduce overlay first)
constexpr int LDS_F = OFF_INVM + MROWS * MCOLS;   // 5424 floats = 21696 B
}

// ---------------------------------------------------------------------------
// Kernel 1: invM (map channel-norms) + left-edge strips.
//   strip [(n*C+c)*H + y][0..3] = {m0,m0,m0,m0}   (m_k = map[n,c,y,k])
//   strip2[(n*C+c)*H + y][0..3] = {m0,m0,m1,m2}   (window starting at x=-1)
// 256 threads = 8 c-groups x 32 q4-pixels; 384 blocks.
// ---------------------------------------------------------------------------
__global__ __launch_bounds__(256)
void norms_kernel(const float* __restrict__ mp,
                  float* __restrict__ invM,
                  float* __restrict__ strip,
                  float* __restrict__ strip2) {
    __shared__ float4 sM[8][32];
    const int tid = threadIdx.x;
    const int cg = tid >> 5;               // 0..7 (8 channels each)
    const int s  = tid & 31;
    const int q4 = blockIdx.x * 32 + s;    // [0, 12288)
    const int n = q4 / (HW / 4);
    const int pix = (q4 - n * (HW / 4)) * 4;
    const int y = pix / W_;
    const int x = pix - y * W_;
    const float* pm = mp + (size_t)n * CHW + pix;
    const bool e = (x == 0);
    float* sp  = strip  + ((size_t)(n * C_ + cg * 8) * H_ + y) * 4;
    float* sp2 = strip2 + ((size_t)(n * C_ + cg * 8) * H_ + y) * 4;

    float4 sm = {0.f, 0.f, 0.f, 0.f};
#pragma unroll
    for (int cc = 0; cc < 8; ++cc) {
        float4 b = *(const float4*)(pm + (size_t)(cc + 0) * HW + (size_t)cg * 8 * HW);
        sm.x = fmaf(b.x, b.x, sm.x); sm.y = fmaf(b.y, b.y, sm.y);
        sm.z = fmaf(b.z, b.z, sm.z); sm.w = fmaf(b.w, b.w, sm.w);
        if (e) {
            float4 v1 = {b.x, b.x, b.x, b.x};
            float4 v2 = {b.x, b.x, b.y, b.z};
            *(float4*)(sp  + (size_t)cc * H_ * 4) = v1;
            *(float4*)(sp2 + (size_t)cc * H_ * 4) = v2;
        }
    }
    sM[cg][s] = sm;
    __syncthreads();
    if (tid < 32) {
        float4 b = sM[0][tid];
#pragma unroll
        for (int g = 1; g < 8; ++g) {
            float4 v = sM[g][tid];
            b.x += v.x; b.y += v.y; b.z += v.z; b.w += v.w;
        }
        int q4b = blockIdx.x * 32 + tid;
        int nb = q4b / (HW / 4);
        int pixb = (q4b - nb * (HW / 4)) * 4;
        float4 vm;
        vm.x = 1.f / (sqrtf(b.x) + EPSV); vm.y = 1.f / (sqrtf(b.y) + EPSV);
        vm.z = 1.f / (sqrtf(b.z) + EPSV); vm.w = 1.f / (sqrtf(b.w) + EPSV);
        *(float4*)(invM + (size_t)nb * HW + pixb) = vm;
    }
}

// ---------------------------------------------------------------------------
// Kernel 2: raw correlation + inline img-norm. No LDS/barriers in main loop.
// Per round: 3 dword-aligned 16B map loads (exact 12-float window) + 1 img
// float4; 40 FMAs. Left edge = pointer redirect to strip/strip2.
//   dotRaw[p,(i,j)] = sum_c map[c, clamp(p+(i,j)-9)] * img[c, p]
//   out_diss = invI[p]*dotRaw ;  out_cos = 1 - invM[p']*out_diss
// ---------------------------------------------------------------------------
__global__ __launch_bounds__(NT)
void corr_kernel(const float* __restrict__ img,
                 const float* __restrict__ mp,
                 const float* __restrict__ invMg,
                 const float* __restrict__ strip,
                 const float* __restrict__ strip2,
                 float* __restrict__ out) {
    __shared__ float smem[LDS_F];

    const int bz = blockIdx.z;             // n*9 + i
    const int n    = bz / RADIUS;
    const int iOff = bz - n * RADIUS;
    const int x0 = blockIdx.x * XT;
    const int y0 = blockIdx.y * YT;
    const int tid = threadIdx.x;
    const int w    = tid >> 6;             // wave = channel group (16 ch)
    const int lane = tid & 63;
    const int ty = lane >> 4;              // 0..3
    const int xc = lane & 15;              // 0..15
    const int ch0 = w * 16;

    const float* imgN = img + (size_t)n * CHW;
    const float* mapN = mp  + (size_t)n * CHW;

    // ---- invM halo (76 float4; epilogue-only, synced by epilogue barrier) ----
    if (tid < MAP_SLOTS) {
        int r = tid / NCH, k = tid - r * NCH;
        int gy = min(max(y0 + iOff - RADIUS + r, 0), H_ - 1);
        int gxs = x0 - 12 + 4 * k;
        const float* src = invMg + n * HW + (size_t)gy * W_;
        float4 v;
        if (gxs >= 0) v = *(const float4*)(src + gxs);
        else { float s0 = src[0]; v.x = s0; v.y = s0; v.z = s0; v.w = s0; }
        *(float4*)&smem[OFF_INVM + r * MCOLS + 4 * k] = v;
    }

    // ---- per-lane direct-read descriptors (3 chunks, window = x0+4xc-9+[0,12)) ----
    const int gy = min(max(y0 + ty + iOff - RADIUS, 0), H_ - 1);
    const float* rowp = mapN + (size_t)ch0 * HW + (size_t)gy * W_;
    const float* stripRow  = strip  + ((size_t)(n * C_ + ch0) * H_ + gy) * 4;
    const float* stripRow2 = strip2 + ((size_t)(n * C_ + ch0) * H_ + gy) * 4;
    const float *pd0, *pd1, *pd2;
    int sd0, sd1, sd2;
    {
        const int gxb = x0 + 4 * xc - 9;
        if (gxb <= -4)     { pd0 = stripRow;  sd0 = H_ * 4; }
        else if (gxb < 0)  { pd0 = stripRow2; sd0 = H_ * 4; }   // gxb == -1
        else               { pd0 = rowp + gxb; sd0 = HW; }
        const int g1 = gxb + 4;
        if (g1 <= -4)      { pd1 = stripRow;  sd1 = H_ * 4; }
        else if (g1 < 0)   { pd1 = stripRow2; sd1 = H_ * 4; }
        else               { pd1 = rowp + g1;  sd1 = HW; }
        const int g2 = gxb + 8;
        if (g2 < 0)        { pd2 = stripRow2; sd2 = H_ * 4; }   // g2 == -1 only
        else               { pd2 = rowp + g2;  sd2 = HW; }
    }
    const float* pI = imgN + (size_t)ch0 * HW + (size_t)(y0 + ty) * W_ + x0 + 4 * xc;

    float acc[4][RADIUS];
#pragma unroll
    for (int p = 0; p < 4; ++p)
#pragma unroll
        for (int j = 0; j < RADIUS; ++j) acc[p][j] = 0.f;
    float si[4] = {0.f, 0.f, 0.f, 0.f};

    // ---- main loop: pure register dataflow, no LDS, no barriers ----
#pragma unroll 4
    for (int ri = 0; ri < ROUNDS; ++ri) {
        float wreg[12];
        __builtin_memcpy(&wreg[0], pd0 + (size_t)ri * sd0, 16);
        __builtin_memcpy(&wreg[4], pd1 + (size_t)ri * sd1, 16);
        __builtin_memcpy(&wreg[8], pd2 + (size_t)ri * sd2, 16);
        const float4 a4 = *(const float4*)(pI + (size_t)ri * HW);
        const float a[4] = {a4.x, a4.y, a4.z, a4.w};
        si[0] = fmaf(a[0], a[0], si[0]);
        si[1] = fmaf(a[1], a[1], si[1]);
        si[2] = fmaf(a[2], a[2], si[2]);
        si[3] = fmaf(a[3], a[3], si[3]);
#pragma unroll
        for (int p = 0; p < 4; ++p)
#pragma unroll
            for (int j = 0; j < RADIUS; ++j)
                acc[p][j] = fmaf(wreg[p + j], a[p], acc[p][j]);
    }

    // ==== epilogue: 4-way cross-wave reduce, SoA float4 layout ====
    __syncthreads();                       // invM halo ready; LDS free
    const int slot = tid;                  // 0..255
#pragma unroll
    for (int q = 0; q < 4; ++q) {
        float4 v = {acc[0][q], acc[1][q], acc[2][q], acc[3][q]};
        *(float4*)&smem[(q * 256 + slot) * 4] = v;
    }
    { float4 v = {si[0], si[1], si[2], si[3]}; *(float4*)&smem[(4 * 256 + slot) * 4] = v; }
    __syncthreads();
    float4 sv = {0.f, 0.f, 0.f, 0.f};
#pragma unroll
    for (int g = 0; g < NW; ++g) {
        float4 v = *(const float4*)&smem[(4 * 256 + g * 64 + lane) * 4];
        sv.x += v.x; sv.y += v.y; sv.z += v.z; sv.w += v.w;
    }
    float4 vI;
    vI.x = 1.f / (sqrtf(sv.x) + EPSV);
    vI.y = 1.f / (sqrtf(sv.y) + EPSV);
    vI.z = 1.f / (sqrtf(sv.z) + EPSV);
    vI.w = 1.f / (sqrtf(sv.w) + EPSV);

    const int y  = y0 + ty;
    const int xb = x0 + 4 * xc;
    const float* wmRow = &smem[OFF_INVM + ty * MCOLS + 4 * xc + 3];
    float* ocB = out + (size_t)(n * 81 + iOff * RADIUS) * HW + (size_t)y * W_ + xb;

    {   // waves 0..3 store j = w
        const int j = w;
        float4 s = {0.f, 0.f, 0.f, 0.f};
#pragma unroll
        for (int g = 0; g < NW; ++g) {
            float4 v = *(const float4*)&smem[(j * 256 + g * 64 + lane) * 4];
            s.x += v.x; s.y += v.y; s.z += v.z; s.w += v.w;
        }
        float4 vd, vc;
        vd.x = s.x * vI.x; vd.y = s.y * vI.y; vd.z = s.z * vI.z; vd.w = s.w * vI.w;
        vc.x = 1.f - vd.x * wmRow[j + 0];
        vc.y = 1.f - vd.y * wmRow[j + 1];
        vc.z = 1.f - vd.z * wmRow[j + 2];
        vc.w = 1.f - vd.w * wmRow[j + 3];
        *(float4*)(ocB + (size_t)j * HW) = vc;
        *(float4*)(ocB + OUT1 + (size_t)j * HW) = vd;
    }
    __syncthreads();
#pragma unroll
    for (int q = 0; q < 5; ++q) {
        float4 v = {acc[0][q + 4], acc[1][q + 4], acc[2][q + 4], acc[3][q + 4]};
        *(float4*)&smem[(q * 256 + slot) * 4] = v;
    }
    __syncthreads();
    {   // waves 0..3 store j = 4 + w
        const int j = 4 + w;
        float4 s = {0.f, 0.f, 0.f, 0.f};
#pragma unroll
        for (int g = 0; g < NW; ++g) {
            float4 v = *(const float4*)&smem[((j - 4) * 256 + g * 64 + lane) * 4];
            s.x += v.x; s.y += v.y; s.z += v.z; s.w += v.w;
        }
        float4 vd, vc;
        vd.x = s.x * vI.x; vd.y = s.y * vI.y; vd.z = s.z * vI.z; vd.w = s.w * vI.w;
        vc.x = 1.f - vd.x * wmRow[j + 0];
        vc.y = 1.f - vd.y * wmRow[j + 1];
        vc.z = 1.f - vd.z * wmRow[j + 2];
        vc.w = 1.f - vd.w * wmRow[j + 3];
        *(float4*)(ocB + (size_t)j * HW) = vc;
        *(float4*)(ocB + OUT1 + (size_t)j * HW) = vd;
    }
    if (w == 0) {                          // wave 0 also stores j = 8
        const int j = 8;
        float4 s = {0.f, 0.f, 0.f, 0.f};
#pragma unroll
        for (int g = 0; g < NW; ++g) {
            float4 v = *(const float4*)&smem[(4 * 256 + g * 64 + lane) * 4];
            s.x += v.x; s.y += v.y; s.z += v.z; s.w += v.w;
        }
        float4 vd, vc;
        vd.x = s.x * vI.x; vd.y = s.y * vI.y; vd.z = s.z * vI.z; vd.w = s.w * vI.w;
        vc.x = 1.f - vd.x * wmRow[j + 0];
        vc.y = 1.f - vd.y * wmRow[j + 1];
        vc.z = 1.f - vd.z * wmRow[j + 2];
        vc.w = 1.f - vd.w * wmRow[j + 3];
        *(float4*)(ocB + (size_t)j * HW) = vc;
        *(float4*)(ocB + OUT1 + (size_t)j * HW) = vd;
    }
}

extern "C" void kernel_launch(void* const* d_in, const int* in_sizes, int n_in,
                              void* d_out, int out_size, void* d_ws, size_t ws_size,
                              hipStream_t stream) {
    const float* img = (const float*)d_in[0];
    const float* mp  = (const float*)d_in[1];
    float* out    = (float*)d_out;
    float* invM   = (float*)d_ws;                 // N_*HW floats
    float* strip  = invM  + N_ * HW;              // N_*C_*H_*4 floats
    float* strip2 = strip + (size_t)N_ * C_ * H_ * 4;

    norms_kernel<<<(N_ * HW / 4) / 32, 256, 0, stream>>>(mp, invM, strip, strip2);

    dim3 grid(W_ / XT, H_ / YT, N_ * RADIUS);     // 3 x 32 x 18 = 1728 blocks
    corr_kernel<<<grid, NT, 0, stream>>>(img, mp, invM, strip, strip2, out);
}